// Round 1
// baseline (2260.645 us; speedup 1.0000x reference)
//
#include <hip/hip_runtime.h>

// Single-pass stable stream compaction with decoupled lookback.
// y[:count] = x[x>0] in original order, y[count:n] = 0, y[out_size-1] = (float)count.
//
// Each block (virtual id = ticket, so id order == execution start order; no
// deadlock regardless of dispatch order) processes one CHUNK of x:
//   load -> count -> block scan -> publish aggregate -> windowed lookback for
//   global exclusive prefix -> publish inclusive prefix -> stage positives in
//   LDS -> coalesced store positives at [excl, excl+total).
// Zerofill is fused: block b writes its (elems - total) zeros at
// [n - zEx - z, n - zEx) where zEx = chunkBase - excl; these regions tile
// [count, n) exactly, so no second pass and no dependence on the total count.

#define BLOCK 256
#define VPT 16               // elems per thread (contiguous)
#define CHUNK (BLOCK * VPT)  // 4096

#define ST_SHIFT 30
#define ST_AGG (1u << ST_SHIFT)   // aggregate available
#define ST_PRE (2u << ST_SHIFT)   // inclusive prefix available
#define VAL_MASK (ST_AGG - 1u)    // value field (n <= 2^26 fits easily)

// Zero flags[0..numBlocks-1] and the ticket counter at flags[numBlocks].
__global__ void k_init(unsigned int* __restrict__ flags, int numBlocks) {
    const int i = blockIdx.x * BLOCK + threadIdx.x;
    if (i <= numBlocks) flags[i] = 0u;
}

// exclusive block scan over 256 threads (4 waves); returns exclusive rank,
// sets *blockTotal. lds must have >= 9 ints.
__device__ __forceinline__ int block_scan_excl_256(int val, int* lds, int* blockTotal) {
    const int tid  = threadIdx.x;
    const int lane = tid & 63;
    const int wave = tid >> 6;
    int incl = val;
#pragma unroll
    for (int off = 1; off < 64; off <<= 1) {
        const int y = __shfl_up(incl, off, 64);
        if (lane >= off) incl += y;
    }
    if (lane == 63) lds[wave] = incl;
    __syncthreads();
    if (tid == 0) {
        const int s0 = lds[0], s1 = lds[1], s2 = lds[2], s3 = lds[3];
        lds[4] = 0; lds[5] = s0; lds[6] = s0 + s1; lds[7] = s0 + s1 + s2;
        lds[8] = s0 + s1 + s2 + s3;
    }
    __syncthreads();
    const int ex = lds[4 + wave] + incl - val;
    *blockTotal = lds[8];
    return ex;
}

__global__ void __launch_bounds__(BLOCK)
k_compact(const float* __restrict__ x, int n, int numBlocks, int out_size,
          unsigned int* __restrict__ flags, float* __restrict__ y) {
    __shared__ float vals[CHUNK];    // 16 KB staging for coalesced output
    __shared__ int scan_lds[9];
    __shared__ unsigned int s_bid;
    __shared__ int s_excl;

    const int tid = threadIdx.x;
    if (tid == 0) s_bid = atomicAdd(&flags[numBlocks], 1u);  // ticket
    __syncthreads();
    const int bid = (int)s_bid;

    const int chunkBase = bid * CHUNK;
    const int tbase = chunkBase + tid * VPT;

    float v[VPT];
    if (tbase + VPT <= n) {
#pragma unroll
        for (int k = 0; k < 4; ++k) {
            const float4 f = *reinterpret_cast<const float4*>(x + tbase + 4 * k);
            v[4 * k + 0] = f.x; v[4 * k + 1] = f.y; v[4 * k + 2] = f.z; v[4 * k + 3] = f.w;
        }
    } else {
#pragma unroll
        for (int j = 0; j < VPT; ++j)
            v[j] = (tbase + j < n) ? x[tbase + j] : 0.f;
    }

    int c = 0;
#pragma unroll
    for (int j = 0; j < VPT; ++j) c += (v[j] > 0.f);

    int total;
    int r = block_scan_excl_256(c, scan_lds, &total);

    // Publish as early as possible so successors can proceed.
    if (tid == 0) {
        const unsigned int pkt = (bid == 0) ? (ST_PRE | (unsigned)total)
                                            : (ST_AGG | (unsigned)total);
        __hip_atomic_store(&flags[bid], pkt, __ATOMIC_RELEASE, __HIP_MEMORY_SCOPE_AGENT);
        if (bid == 0) s_excl = 0;
    }

    // Wave 0: windowed lookback (64 predecessors per probe). Waves 1-3 fall
    // through to LDS staging meanwhile.
    if (bid != 0 && tid < 64) {
        const int lane = tid;
        int running = 0;
        int pb = bid - 1;
        for (;;) {
            const int idx = pb - lane;
            unsigned int f;
            if (idx >= 0) {
                f = __hip_atomic_load(&flags[idx], __ATOMIC_ACQUIRE, __HIP_MEMORY_SCOPE_AGENT);
                while ((f >> ST_SHIFT) == 0u) {
                    __builtin_amdgcn_s_sleep(1);
                    f = __hip_atomic_load(&flags[idx], __ATOMIC_ACQUIRE, __HIP_MEMORY_SCOPE_AGENT);
                }
            } else {
                f = ST_PRE;  // synthetic prefix 0 before block 0
            }
            const bool isPre = (f >> ST_SHIFT) == 2u;
            const unsigned long long ball = __ballot(isPre);
            const int firstPre = ball ? (int)__builtin_ctzll(ball) : 64;
            int contrib = (lane <= firstPre) ? (int)(f & VAL_MASK) : 0;
#pragma unroll
            for (int off = 1; off < 64; off <<= 1) contrib += __shfl_xor(contrib, off, 64);
            running += contrib;
            if (ball) break;   // found an inclusive prefix in this window
            pb -= 64;
        }
        if (lane == 0) {
            s_excl = running;
            __hip_atomic_store(&flags[bid], ST_PRE | (unsigned)(running + total),
                               __ATOMIC_RELEASE, __HIP_MEMORY_SCOPE_AGENT);
        }
    }

    // Stage positives (stable order) into LDS.
#pragma unroll
    for (int j = 0; j < VPT; ++j) {
        if (v[j] > 0.f) vals[r++] = v[j];
    }
    __syncthreads();

    const int excl = s_excl;

    // Coalesced store of the compacted positives.
    for (int j = tid; j < total; j += BLOCK) {
        y[excl + j] = vals[j];
    }

    // Fused zerofill: this block's zeros tile a slice of [count, n) from the top.
    const int rem   = n - chunkBase;
    const int elems = rem < CHUNK ? rem : CHUNK;
    const int z     = elems - total;
    const int zhi   = n - (chunkBase - excl);
    const int zlo   = zhi - z;
    for (int j = tid; j < z; j += BLOCK) {
        y[zlo + j] = 0.f;
    }

    if (bid == numBlocks - 1 && tid == 0) {
        y[out_size - 1] = (float)(excl + total);
    }
}

extern "C" void kernel_launch(void* const* d_in, const int* in_sizes, int n_in,
                              void* d_out, int out_size, void* d_ws, size_t ws_size,
                              hipStream_t stream) {
    const float* x = (const float*)d_in[0];
    float* y = (float*)d_out;
    const int n = in_sizes[0];

    unsigned int* flags = (unsigned int*)d_ws;          // numBlocks flags + 1 ticket
    const int numBlocks = (n + CHUNK - 1) / CHUNK;      // 16384 for N=64M

    const int initBlocks = (numBlocks + 1 + BLOCK - 1) / BLOCK;
    k_init<<<initBlocks, BLOCK, 0, stream>>>(flags, numBlocks);
    k_compact<<<numBlocks, BLOCK, 0, stream>>>(x, n, numBlocks, out_size, flags, y);
}

// Round 2
// 493.689 us; speedup vs baseline: 4.5791x; 4.5791x over previous
//
#include <hip/hip_runtime.h>

// Stable stream compaction: y[:count] = x[x>0] in original order, y[count:n]=0,
// y[out_size-1] = (float)count.
//
// reduce-then-scan, 3 kernels, no inter-block waiting (lookback was measured
// latency-bound at 2.7% HBM — never chain 16K blocks):
//   k_count   : per-block positive count, perfectly coalesced float4 loads
//   k_scan    : single-block exclusive scan of 16384 block sums + count out
//   k_scatter : re-read x (position-ordered), LDS-stage, coalesced store,
//               FUSED zerofill (block-local algebra, no global-count dep).

#define BLOCK 256
#define VPT 16               // elems per thread (contiguous, scatter only)
#define CHUNK (BLOCK * VPT)  // 4096
#define SCAN_THREADS 1024
#define SCAN_VPT 16          // scan supports up to 16384 block sums

__global__ void __launch_bounds__(BLOCK)
k_count(const float* __restrict__ x, int n, int* __restrict__ blockSums) {
    const int tid = threadIdx.x;
    const long long chunkBase = (long long)blockIdx.x * CHUNK;
    int cnt = 0;
    if (chunkBase + CHUNK <= n) {
        // coalesced: lane-contiguous float4, 4 rounds of 1024 elems
        const float* p = x + chunkBase + tid * 4;
#pragma unroll
        for (int it = 0; it < 4; ++it) {
            const float4 v = *reinterpret_cast<const float4*>(p + it * (BLOCK * 4));
            cnt += (v.x > 0.f) + (v.y > 0.f) + (v.z > 0.f) + (v.w > 0.f);
        }
    } else {
        const long long lim = (chunkBase + CHUNK < n) ? chunkBase + CHUNK : n;
        for (long long j = chunkBase + tid; j < lim; j += BLOCK) cnt += (x[j] > 0.f);
    }
#pragma unroll
    for (int off = 32; off > 0; off >>= 1) cnt += __shfl_down(cnt, off, 64);
    __shared__ int lds[4];
    if ((tid & 63) == 0) lds[tid >> 6] = cnt;
    __syncthreads();
    if (tid == 0) blockSums[blockIdx.x] = lds[0] + lds[1] + lds[2] + lds[3];
}

// Single-block exclusive scan of blockSums (numBlocks <= SCAN_THREADS*SCAN_VPT).
__global__ void k_scan(int* __restrict__ sums, int numBlocks,
                       int* __restrict__ countOut, float* __restrict__ countOutF) {
    __shared__ int lds[32];
    const int tid  = threadIdx.x;
    const int lane = tid & 63;
    const int wave = tid >> 6;   // 16 waves

    int vals[SCAN_VPT];
    const int base = tid * SCAN_VPT;
    int local = 0;
#pragma unroll
    for (int j = 0; j < SCAN_VPT; ++j) {
        const int i = base + j;
        const int v = (i < numBlocks) ? sums[i] : 0;
        vals[j] = local;         // thread-local exclusive
        local += v;
    }
    int incl = local;
#pragma unroll
    for (int off = 1; off < 64; off <<= 1) {
        const int y = __shfl_up(incl, off, 64);
        if (lane >= off) incl += y;
    }
    if (lane == 63) lds[wave] = incl;
    __syncthreads();
    if (wave == 0 && lane < 16) {
        int w = lds[lane];
#pragma unroll
        for (int off = 1; off < 16; off <<= 1) {
            const int y = __shfl_up(w, off, 16);
            if ((lane & 15) >= off) w += y;
        }
        lds[16 + lane] = w;      // inclusive wave prefix
    }
    __syncthreads();
    const int waveEx   = (wave == 0) ? 0 : lds[16 + wave - 1];
    const int threadEx = waveEx + incl - local;
#pragma unroll
    for (int j = 0; j < SCAN_VPT; ++j) {
        const int i = base + j;
        if (i < numBlocks) sums[i] = threadEx + vals[j];
    }
    if (tid == SCAN_THREADS - 1) {
        const int total = waveEx + incl;
        *countOut  = total;
        *countOutF = (float)total;
    }
}

// exclusive block scan over 256 threads (4 waves); returns exclusive rank,
// sets *blockTotal. lds must have >= 9 ints.
__device__ __forceinline__ int block_scan_excl_256(int val, int* lds, int* blockTotal) {
    const int tid  = threadIdx.x;
    const int lane = tid & 63;
    const int wave = tid >> 6;
    int incl = val;
#pragma unroll
    for (int off = 1; off < 64; off <<= 1) {
        const int y = __shfl_up(incl, off, 64);
        if (lane >= off) incl += y;
    }
    if (lane == 63) lds[wave] = incl;
    __syncthreads();
    if (tid == 0) {
        const int s0 = lds[0], s1 = lds[1], s2 = lds[2], s3 = lds[3];
        lds[4] = 0; lds[5] = s0; lds[6] = s0 + s1; lds[7] = s0 + s1 + s2;
        lds[8] = s0 + s1 + s2 + s3;
    }
    __syncthreads();
    const int ex = lds[4 + wave] + incl - val;
    *blockTotal = lds[8];
    return ex;
}

__global__ void __launch_bounds__(BLOCK)
k_scatter(const float* __restrict__ x, int n,
          const int* __restrict__ blockOffsets, float* __restrict__ y) {
    __shared__ float vals[CHUNK];   // 16 KB staging
    __shared__ int scan_lds[9];
    const int tid = threadIdx.x;
    const int chunkBase = blockIdx.x * CHUNK;
    const long long tbase = (long long)chunkBase + tid * VPT;

    float v[VPT];
    if ((long long)chunkBase + CHUNK <= n) {
#pragma unroll
        for (int k = 0; k < 4; ++k) {
            const float4 f = *reinterpret_cast<const float4*>(x + tbase + 4 * k);
            v[4 * k + 0] = f.x; v[4 * k + 1] = f.y; v[4 * k + 2] = f.z; v[4 * k + 3] = f.w;
        }
    } else {
#pragma unroll
        for (int j = 0; j < VPT; ++j)
            v[j] = (tbase + j < n) ? x[tbase + j] : 0.f;
    }

    int c = 0;
#pragma unroll
    for (int j = 0; j < VPT; ++j) c += (v[j] > 0.f);

    int total;
    int r = block_scan_excl_256(c, scan_lds, &total);

#pragma unroll
    for (int j = 0; j < VPT; ++j) {
        if (v[j] > 0.f) vals[r++] = v[j];
    }
    __syncthreads();

    const int excl = blockOffsets[blockIdx.x];

    // Coalesced store of the compacted positives.
    for (int j = tid; j < total; j += BLOCK) {
        y[excl + j] = vals[j];
    }

    // Fused zerofill: this block's zeros tile a slice of [count, n) from the
    // top down; regions are disjoint and cover [count, n) exactly, with no
    // dependence on the global count.
    const int rem   = n - chunkBase;
    const int elems = rem < CHUNK ? rem : CHUNK;
    const int z     = elems - total;
    const long long zhi = (long long)n - (chunkBase - excl);
    const long long zlo = zhi - z;
    for (int j = tid; j < z; j += BLOCK) {
        y[zlo + j] = 0.f;
    }
}

extern "C" void kernel_launch(void* const* d_in, const int* in_sizes, int n_in,
                              void* d_out, int out_size, void* d_ws, size_t ws_size,
                              hipStream_t stream) {
    const float* x = (const float*)d_in[0];
    float* y = (float*)d_out;
    const int n = in_sizes[0];

    int* blockSums = (int*)d_ws;
    const int numBlocks = (n + CHUNK - 1) / CHUNK;   // 16384 for N=64M
    int* countPtr = blockSums + numBlocks;

    k_count<<<numBlocks, BLOCK, 0, stream>>>(x, n, blockSums);
    k_scan<<<1, SCAN_THREADS, 0, stream>>>(blockSums, numBlocks,
                                           countPtr, y + (out_size - 1));
    k_scatter<<<numBlocks, BLOCK, 0, stream>>>(x, n, blockSums, y);
}